// Round 6
// baseline (1133.342 us; speedup 1.0000x reference)
//
#include <hip/hip_runtime.h>
#include <math.h>

// DistanceEncoderHSTLSTM: out[e][:] = hd*embed[lb] + ld*embed[hb]
// N = 4,194,304 elements, DIM = 64, NSLOTS = 16.
// Memory-bound: 1.07 GB of streaming fp32 writes dominates (floor ~173 us @6.3 TB/s).

constexpr int NSLOTS = 16;
constexpr int DIM    = 64;

__global__ __launch_bounds__(256) void dist_enc_kernel(
    const float* __restrict__ dist,
    const float* __restrict__ embed,   // [NSLOTS][DIM]
    const float* __restrict__ slots,   // [NSLOTS], sorted ascending
    float* __restrict__ out,           // [N][DIM]
    int n)
{
    __shared__ float s_embed[NSLOTS * DIM];   // 4 KB

    const int t = threadIdx.x;

    // Stage embed table: 256 threads x float4 = 1024 floats = 16x64. One shot.
    ((float4*)s_embed)[t] = ((const float4*)embed)[t];
    __syncthreads();

    // Slots are wave-uniform -> scalar loads into registers.
    float sl[NSLOTS];
    #pragma unroll
    for (int i = 0; i < NSLOTS; ++i) sl[i] = slots[i];

    // 16 threads per element: group g handles element, lane-in-group c writes cols [4c, 4c+4).
    const int g  = t >> 4;
    const int c4 = (t & 15) << 2;
    const int estride = (int)(gridDim.x * 16);

    for (int e = (int)(blockIdx.x * 16) + g; e < n; e += estride) {
        const float d = dist[e];

        // searchsorted(slots, d, side='right'): hb = #slots <= d.
        // Track lo_s = largest slot <= d, hi_s = smallest slot > d via selects
        // (NO runtime-indexed register array -> stays in VGPRs).
        int   hb   = 0;
        float lo_s = sl[0];
        float hi_s = INFINITY;
        #pragma unroll
        for (int i = 0; i < NSLOTS; ++i) {
            const bool le = (sl[i] <= d);
            hb   += le ? 1 : 0;
            lo_s  = le ? sl[i] : lo_s;
            hi_s  = (!le && (sl[i] < hi_s)) ? sl[i] : hi_s;
        }

        const bool at_end = (hb == NSLOTS);
        int lb = hb - 1;
        if (lb < 0) lb = 0;
        int hi = at_end ? lb : hb;
        if (hi > NSLOTS - 1) hi = NSLOTS - 1;

        // Branchless weights (at_end lanes discard the division results).
        const float total = at_end ? 1.0f : (hi_s - lo_s);
        const float ld    = at_end ? 1.0f : (d - lo_s) / total;
        const float hd    = at_end ? 0.0f : (hi_s - d) / total;

        // Gather two float4 fragments from LDS (runtime row index is fine in LDS).
        const float4 lw = *(const float4*)&s_embed[lb * DIM + c4];
        const float4 hw = *(const float4*)&s_embed[hi * DIM + c4];

        float4 o;
        o.x = hd * lw.x + ld * hw.x;
        o.y = hd * lw.y + ld * hw.y;
        o.z = hd * lw.z + ld * hw.z;
        o.w = hd * lw.w + ld * hw.w;

        // Contiguous 4 KB per block-iteration: perfectly coalesced dwordx4 stores.
        *(float4*)&out[(size_t)e * DIM + c4] = o;
    }
}

extern "C" void kernel_launch(void* const* d_in, const int* in_sizes, int n_in,
                              void* d_out, int out_size, void* d_ws, size_t ws_size,
                              hipStream_t stream) {
    const float* dist  = (const float*)d_in[0];
    const float* embed = (const float*)d_in[1];
    const float* slots = (const float*)d_in[2];
    float* out = (float*)d_out;
    const int n = in_sizes[0];

    int blocks = (n + 15) / 16;
    if (blocks > 2048) blocks = 2048;   // full residency: 2048 blocks x 4 waves = 8192 waves

    hipLaunchKernelGGL(dist_enc_kernel, dim3(blocks), dim3(256), 0, stream,
                       dist, embed, slots, out, n);
}